// Round 11
// baseline (125.231 us; speedup 1.0000x reference)
//
#include <hip/hip_runtime.h>

#define IMG_H 1080
#define IMG_W 1920
#define CH 3

__global__ __launch_bounds__(192)
void dssim_l1_kernel(const float* __restrict__ pred,
                     const float* __restrict__ gt,
                     float* __restrict__ out) {
    constexpr float K1 = 81.0f * 0.0001f;        // 81*C1
    constexpr float K2 = 81.0f * 0.0009f;        // 81*C2
    constexpr float A3 = 0.85f / 3.0f;
    constexpr float B3 = 0.15f / 3.0f;

    const int lane = threadIdx.x;                // 0..63
    const int sl   = lane & 31;                  // lane within half-wave
    const int hh   = lane >> 5;                  // half 0/1
    const int ty   = threadIdx.y;                // 0..2
    const int b    = blockIdx.z;

    const int c0 = blockIdx.x * 128 + sl * 4;            // 4 aligned cols
    const int r0 = blockIdx.y * 12 + ty * 4 + hh * 2;    // rows r0, r0+1

    // input rows r0-1 .. r0+2 with reflection
    const int rws[4] = { (r0 == 0) ? 1 : r0 - 1, r0, r0 + 1,
                         (r0 + 2 == IMG_H) ? IMG_H - 2 : r0 + 2 };

    const bool sl0 = (sl == 0), sl31 = (sl == 31);
    const bool is_edge = sl0 || sl31;
    const bool limg = sl0  && (blockIdx.x == 0);    // image left edge
    const bool rimg = sl31 && (blockIdx.x == 14);   // image right edge
    const int  hcol = sl0 ? max(c0 - 1, 0) : min(c0 + 4, IMG_W - 1);

    const size_t img = (size_t)IMG_H * IMG_W;
    const float* __restrict__ bx = pred + (size_t)b * CH * img;
    const float* __restrict__ by = gt   + (size_t)b * CH * img;

    // ---- issue all 24 float4 loads (+ predicated halo) upfront ----
    float4 xq[4][CH], yq[4][CH];
    float hx[4][CH], hy[4][CH];
#pragma unroll
    for (int i = 0; i < 4; ++i) {
        const unsigned ro = (unsigned)rws[i] * IMG_W;
#pragma unroll
        for (int c = 0; c < CH; ++c) {
            const size_t base = (size_t)c * img + ro;
            xq[i][c] = *reinterpret_cast<const float4*>(bx + base + c0);
            yq[i][c] = *reinterpret_cast<const float4*>(by + base + c0);
        }
    }
    if (is_edge) {
#pragma unroll
        for (int i = 0; i < 4; ++i) {
#pragma unroll
            for (int c = 0; c < CH; ++c) {
                const size_t base = (size_t)c * img + (unsigned)rws[i] * IMG_W;
                hx[i][c] = bx[base + hcol];
                hy[i][c] = by[base + hcol];
            }
        }
    }

    // accumulators: [ch][col 0..3], stats x, y, w=xx+yy, p=xy
    float Ax[CH][4], Ay[CH][4], Aw[CH][4], Ap[CH][4];   // rows 0,1,2 -> out r0
    float Bx[CH][4], By[CH][4], Bw[CH][4], Bp[CH][4];   // rows 1,2,3 -> out r0+1
    float l1A[4], l1B[4];

#define CONSUME(I, DOA, FIRSTA, DOB, FIRSTB, L1V)                           \
    _Pragma("unroll")                                                       \
    for (int c = 0; c < CH; ++c) {                                          \
        const float4 qx = xq[I][c], qy = yq[I][c];                          \
        float xm = __shfl_up(qx.w, 1, 32), ym = __shfl_up(qy.w, 1, 32);     \
        float xp = __shfl_down(qx.x, 1, 32), yp = __shfl_down(qy.x, 1, 32); \
        if (sl0)  { xm = hx[I][c]; ym = hy[I][c]; }                         \
        if (sl31) { xp = hx[I][c]; yp = hy[I][c]; }                         \
        if (limg) { xm = qx.y; ym = qy.y; }      /* reflect(-1)=1 */        \
        if (rimg) { xp = qx.z; yp = qy.z; }      /* reflect(1920)=1918 */   \
        const float tx[6] = { xm, qx.x, qx.y, qx.z, qx.w, xp };             \
        const float ty_[6] = { ym, qy.x, qy.y, qy.z, qy.w, yp };            \
        if (L1V) {                                                          \
            _Pragma("unroll")                                               \
            for (int j = 0; j < 4; ++j) {                                   \
                const float d_ = fabsf(tx[j + 1] - ty_[j + 1]);             \
                if (c == 0) L1V[j] = d_; else L1V[j] += d_;                 \
            }                                                               \
        }                                                                   \
        float pw[6], pp[6];                                                 \
        _Pragma("unroll")                                                   \
        for (int t = 0; t < 6; ++t) {                                       \
            pw[t] = fmaf(tx[t], tx[t], ty_[t] * ty_[t]);                    \
            pp[t] = tx[t] * ty_[t];                                         \
        }                                                                   \
        _Pragma("unroll")                                                   \
        for (int j = 0; j < 4; ++j) {                                       \
            const float sx_ = tx[j] + tx[j + 1] + tx[j + 2];                \
            const float sy_ = ty_[j] + ty_[j + 1] + ty_[j + 2];             \
            const float sw_ = pw[j] + pw[j + 1] + pw[j + 2];                \
            const float sp_ = pp[j] + pp[j + 1] + pp[j + 2];                \
            if (DOA) {                                                      \
                if (FIRSTA) { Ax[c][j] = sx_; Ay[c][j] = sy_;               \
                              Aw[c][j] = sw_; Ap[c][j] = sp_; }             \
                else        { Ax[c][j] += sx_; Ay[c][j] += sy_;             \
                              Aw[c][j] += sw_; Ap[c][j] += sp_; }           \
            }                                                               \
            if (DOB) {                                                      \
                if (FIRSTB) { Bx[c][j] = sx_; By[c][j] = sy_;               \
                              Bw[c][j] = sw_; Bp[c][j] = sp_; }             \
                else        { Bx[c][j] += sx_; By[c][j] += sy_;             \
                              Bw[c][j] += sw_; Bp[c][j] += sp_; }           \
            }                                                               \
        }                                                                   \
    }

    CONSUME(0, true, true,  false, false, ((float*)0))   // row r0-1 -> A
    CONSUME(1, true, false, true,  true,  l1A)           // row r0   -> A,B
    CONSUME(2, true, false, true,  false, l1B)           // row r0+1 -> A,B
    CONSUME(3, false, false, true, false, ((float*)0))   // row r0+2 -> B
#undef CONSUME

    // ---- SSIM epilogue (moments scaled by 81; cancels in n/d) ----
#define SSIM(AX, AY, AW, AP, ACC)                                           \
    {                                                                       \
        const float u = (AX) * (AY);                                        \
        const float v = fmaf((AY), (AY), (AX) * (AX));                      \
        const float num1 = fmaf(2.0f, u, K1);                               \
        const float num2 = fmaf(18.0f, (AP), fmaf(-2.0f, u, K2));           \
        const float den1 = v + K1;                                          \
        const float den2 = fmaf(9.0f, (AW), K2) - v;                        \
        float s = fmaf(-0.5f, (num1 * num2) *                               \
                       __builtin_amdgcn_rcpf(den1 * den2), 0.5f);           \
        s = fminf(fmaxf(s, 0.0f), 1.0f);                                    \
        ACC = fmaf(A3, s, ACC);                                             \
    }

    float r0v[4], r1v[4];
#pragma unroll
    for (int j = 0; j < 4; ++j) {
        float a0 = B3 * l1A[j];
        float a1 = B3 * l1B[j];
#pragma unroll
        for (int c = 0; c < CH; ++c) {
            SSIM(Ax[c][j], Ay[c][j], Aw[c][j], Ap[c][j], a0)
            SSIM(Bx[c][j], By[c][j], Bw[c][j], Bp[c][j], a1)
        }
        r0v[j] = a0; r1v[j] = a1;
    }
#undef SSIM

    float* op = out + ((size_t)b * IMG_H + r0) * IMG_W + c0;
    float4 o0; o0.x = r0v[0]; o0.y = r0v[1]; o0.z = r0v[2]; o0.w = r0v[3];
    float4 o1; o1.x = r1v[0]; o1.y = r1v[1]; o1.z = r1v[2]; o1.w = r1v[3];
    *reinterpret_cast<float4*>(op) = o0;
    *reinterpret_cast<float4*>(op + IMG_W) = o1;
}

extern "C" void kernel_launch(void* const* d_in, const int* in_sizes, int n_in,
                              void* d_out, int out_size, void* d_ws, size_t ws_size,
                              hipStream_t stream) {
    const float* pred = (const float*)d_in[0];
    const float* gt   = (const float*)d_in[1];
    float* out = (float*)d_out;

    dim3 block(64, 3, 1);
    dim3 grid(IMG_W / 128, IMG_H / 12, 4);   // 15 x 90 x 4
    dssim_l1_kernel<<<grid, block, 0, stream>>>(pred, gt, out);
}

// Round 12
// 59.934 us; speedup vs baseline: 2.0895x; 2.0895x over previous
//
#include <hip/hip_runtime.h>

#define IMG_H 1080
#define IMG_W 1920
#define CH 3

__global__ __launch_bounds__(256)
void dssim_l1_kernel(const float* __restrict__ pred,
                     const float* __restrict__ gt,
                     float* __restrict__ out) {
    constexpr float K1 = 81.0f * 0.0001f;        // 81*C1
    constexpr float K2 = 81.0f * 0.0009f;        // 81*C2
    constexpr float A3 = 0.85f / 3.0f;
    constexpr float B3 = 0.15f / 3.0f;

    const int lane = threadIdx.x;                               // 0..63
    const int r0   = (blockIdx.y * 4 + threadIdx.y) * 2;        // even output row
    const int b    = blockIdx.z;
    const int c0   = blockIdx.x * 128 + 2 * lane;               // 2 output cols

    // input rows r0-1 .. r0+2 with reflection
    const int rws[4] = { (r0 == 0) ? 1 : r0 - 1,
                         r0, r0 + 1,
                         (r0 + 2 == IMG_H) ? IMG_H - 2 : r0 + 2 };

    const bool l0 = (lane == 0), l63 = (lane == 63);
    const bool limg = l0  && (blockIdx.x == 0);    // image left edge lane
    const bool rimg = l63 && (blockIdx.x == 14);   // image right edge lane
    const int  hcol = l0 ? max(c0 - 1, 0) : min(c0 + 2, IMG_W - 1);
    const bool is_edge = l0 || l63;

    const size_t img = (size_t)IMG_H * IMG_W;
    const float* __restrict__ pb[2 * CH] = {
        pred + (size_t)b * CH * img,
        pred + (size_t)b * CH * img + img,
        pred + (size_t)b * CH * img + 2 * img,
        gt   + (size_t)b * CH * img,
        gt   + (size_t)b * CH * img + img,
        gt   + (size_t)b * CH * img + 2 * img };

    // shared 32-bit voffsets (one per input row, reused across all 6 planes)
    unsigned off[4];
#pragma unroll
    for (int i = 0; i < 4; ++i) off[i] = (unsigned)rws[i] * IMG_W + (unsigned)c0;

    // ---- halo loads FIRST (so the first consume's wait leaves the main
    //      queue deep; issuing these last forced a full drain in R9) ----
    float hx[4][CH], hy[4][CH];
    if (is_edge) {
        const unsigned hbase = (unsigned)hcol - (unsigned)c0;  // constant delta
#pragma unroll
        for (int i = 0; i < 4; ++i) {
            const unsigned ho = off[i] + hbase;
#pragma unroll
            for (int c = 0; c < CH; ++c) {
                hx[i][c] = pb[c][ho];
                hy[i][c] = pb[CH + c][ho];
            }
        }
    }

    // ---- main 24 float2 loads ----
    float2 qx[4][CH], qy[4][CH];
#pragma unroll
    for (int i = 0; i < 4; ++i) {
#pragma unroll
        for (int c = 0; c < CH; ++c) {
            qx[i][c] = *reinterpret_cast<const float2*>(pb[c]      + off[i]);
            qy[i][c] = *reinterpret_cast<const float2*>(pb[CH + c] + off[i]);
        }
    }

    // window accumulators: [ch][col j] for stats x, y, w=xx+yy, p=xy
    float Ax[CH][2], Ay[CH][2], Aw[CH][2], Ap[CH][2];   // rows -1,0,1 -> out r0
    float Bx[CH][2], By[CH][2], Bw[CH][2], Bp[CH][2];   // rows 0,1,2  -> out r0+1

#define CONSUME(I, DOA, FIRSTA, DOB, FIRSTB)                                \
    _Pragma("unroll")                                                       \
    for (int c = 0; c < CH; ++c) {                                          \
        const float2 qx_ = qx[I][c], qy_ = qy[I][c];                        \
        float xm = __shfl_up(qx_.y, 1), ym = __shfl_up(qy_.y, 1);           \
        float xp = __shfl_down(qx_.x, 1), yp = __shfl_down(qy_.x, 1);       \
        if (l0)   { xm = hx[I][c]; ym = hy[I][c]; }                         \
        if (l63)  { xp = hx[I][c]; yp = hy[I][c]; }                         \
        if (limg) { xm = qx_.y; ym = qy_.y; }      /* reflect(-1)=1 */      \
        if (rimg) { xp = qx_.x; yp = qy_.x; }      /* reflect(1920)=1918 */ \
        const float tx[4] = { xm, qx_.x, qx_.y, xp };                       \
        const float ty[4] = { ym, qy_.x, qy_.y, yp };                       \
        float pw[4], pp[4];                                                 \
        _Pragma("unroll")                                                   \
        for (int t = 0; t < 4; ++t) {                                       \
            pw[t] = fmaf(tx[t], tx[t], ty[t] * ty[t]);                      \
            pp[t] = tx[t] * ty[t];                                          \
        }                                                                   \
        const float mx = tx[1] + tx[2], my = ty[1] + ty[2];                 \
        const float mw = pw[1] + pw[2], mp = pp[1] + pp[2];                 \
        const float wx0 = mx + tx[0], wx1 = mx + tx[3];                     \
        const float wy0 = my + ty[0], wy1 = my + ty[3];                     \
        const float ww0 = mw + pw[0], ww1 = mw + pw[3];                     \
        const float wp0 = mp + pp[0], wp1 = mp + pp[3];                     \
        if (DOA) {                                                          \
            if (FIRSTA) { Ax[c][0]=wx0; Ax[c][1]=wx1; Ay[c][0]=wy0;         \
                          Ay[c][1]=wy1; Aw[c][0]=ww0; Aw[c][1]=ww1;         \
                          Ap[c][0]=wp0; Ap[c][1]=wp1; }                     \
            else        { Ax[c][0]+=wx0; Ax[c][1]+=wx1; Ay[c][0]+=wy0;      \
                          Ay[c][1]+=wy1; Aw[c][0]+=ww0; Aw[c][1]+=ww1;      \
                          Ap[c][0]+=wp0; Ap[c][1]+=wp1; }                   \
        }                                                                   \
        if (DOB) {                                                          \
            if (FIRSTB) { Bx[c][0]=wx0; Bx[c][1]=wx1; By[c][0]=wy0;         \
                          By[c][1]=wy1; Bw[c][0]=ww0; Bw[c][1]=ww1;         \
                          Bp[c][0]=wp0; Bp[c][1]=wp1; }                     \
            else        { Bx[c][0]+=wx0; Bx[c][1]+=wx1; By[c][0]+=wy0;      \
                          By[c][1]+=wy1; Bw[c][0]+=ww0; Bw[c][1]+=ww1;      \
                          Bp[c][0]+=wp0; Bp[c][1]+=wp1; }                   \
        }                                                                   \
    }

    CONSUME(0, true, true,  false, false)   // row r0-1 -> A
    CONSUME(1, true, false, true,  true)    // row r0   -> A, B
    CONSUME(2, true, false, true,  false)   // row r0+1 -> A, B
    CONSUME(3, false, false, true, false)   // row r0+2 -> B
#undef CONSUME

    // L1 terms from raw center rows (index 1 -> out r0, index 2 -> out r0+1)
    float l1r0c0 = 0.f, l1r0c1 = 0.f, l1r1c0 = 0.f, l1r1c1 = 0.f;
#pragma unroll
    for (int c = 0; c < CH; ++c) {
        l1r0c0 += fabsf(qx[1][c].x - qy[1][c].x);
        l1r0c1 += fabsf(qx[1][c].y - qy[1][c].y);
        l1r1c0 += fabsf(qx[2][c].x - qy[2][c].x);
        l1r1c1 += fabsf(qx[2][c].y - qy[2][c].y);
    }

    // ---- SSIM epilogue (moments scaled by 81; cancels in n/d) ----
#define SSIM(AX, AY, AW, AP, ACC)                                           \
    {                                                                       \
        const float u = (AX) * (AY);                                        \
        const float v = fmaf((AY), (AY), (AX) * (AX));                      \
        const float num1 = fmaf(2.0f, u, K1);                               \
        const float num2 = fmaf(18.0f, (AP), fmaf(-2.0f, u, K2));           \
        const float den1 = v + K1;                                          \
        const float den2 = fmaf(9.0f, (AW), K2) - v;                        \
        float s = fmaf(-0.5f, (num1 * num2) *                               \
                       __builtin_amdgcn_rcpf(den1 * den2), 0.5f);           \
        s = __builtin_amdgcn_fmed3f(s, 0.0f, 1.0f);                         \
        ACC = fmaf(A3, s, ACC);                                             \
    }

    float o00 = B3 * l1r0c0, o01 = B3 * l1r0c1;
    float o10 = B3 * l1r1c0, o11 = B3 * l1r1c1;
#pragma unroll
    for (int c = 0; c < CH; ++c) {
        SSIM(Ax[c][0], Ay[c][0], Aw[c][0], Ap[c][0], o00)
        SSIM(Ax[c][1], Ay[c][1], Aw[c][1], Ap[c][1], o01)
        SSIM(Bx[c][0], By[c][0], Bw[c][0], Bp[c][0], o10)
        SSIM(Bx[c][1], By[c][1], Bw[c][1], Bp[c][1], o11)
    }
#undef SSIM

    float* op = out + ((size_t)b * IMG_H + r0) * IMG_W + c0;
    float2 v0; v0.x = o00; v0.y = o01;
    float2 v1; v1.x = o10; v1.y = o11;
    *reinterpret_cast<float2*>(op) = v0;
    *reinterpret_cast<float2*>(op + IMG_W) = v1;
}

extern "C" void kernel_launch(void* const* d_in, const int* in_sizes, int n_in,
                              void* d_out, int out_size, void* d_ws, size_t ws_size,
                              hipStream_t stream) {
    const float* pred = (const float*)d_in[0];
    const float* gt   = (const float*)d_in[1];
    float* out = (float*)d_out;

    dim3 block(64, 4, 1);
    dim3 grid(IMG_W / 128, IMG_H / 8, 4);   // 15 x 135 x 4
    dssim_l1_kernel<<<grid, block, 0, stream>>>(pred, gt, out);
}

// Round 13
// 57.439 us; speedup vs baseline: 2.1803x; 1.0435x over previous
//
#include <hip/hip_runtime.h>

#define IMG_H 1080
#define IMG_W 1920
#define CH 3

typedef float f32x2 __attribute__((ext_vector_type(2)));

#if __has_builtin(__builtin_elementwise_fma)
#define FMA2(a, b, c) __builtin_elementwise_fma((a), (b), (c))
#else
#define FMA2(a, b, c) ((a) * (b) + (c))
#endif

__global__ __launch_bounds__(256)
void dssim_l1_kernel(const float* __restrict__ pred,
                     const float* __restrict__ gt,
                     float* __restrict__ out) {
    constexpr float K1 = 81.0f * 0.0001f;        // 81*C1
    constexpr float K2 = 81.0f * 0.0009f;        // 81*C2

    // packed constants (splat)
    const f32x2 k1_ = K1, k2_ = K2;
    const f32x2 two_ = 2.0f, m2_ = -2.0f, e18_ = 18.0f, n9_ = 9.0f;
    const f32x2 mh_ = -0.5f, h_ = 0.5f, zero_ = 0.0f, one_ = 1.0f;
    const f32x2 a3_ = 0.85f / 3.0f, b3_ = 0.15f / 3.0f;

    const int lane = threadIdx.x;                               // 0..63
    const int r0   = (blockIdx.y * 4 + threadIdx.y) * 2;        // even output row
    const int b    = blockIdx.z;
    const int c0   = blockIdx.x * 128 + 2 * lane;               // 2 output cols

    // input rows r0-1 .. r0+2 with reflection
    const int rws[4] = { (r0 == 0) ? 1 : r0 - 1,
                         r0, r0 + 1,
                         (r0 + 2 == IMG_H) ? IMG_H - 2 : r0 + 2 };

    const bool l0 = (lane == 0), l63 = (lane == 63);
    const bool limg = l0  && (blockIdx.x == 0);    // image left edge lane
    const bool rimg = l63 && (blockIdx.x == 14);   // image right edge lane
    const int  hcol = l0 ? max(c0 - 1, 0) : min(c0 + 2, IMG_W - 1);
    const bool is_edge = l0 || l63;

    const size_t img = (size_t)IMG_H * IMG_W;
    const float* __restrict__ pb[2 * CH] = {
        pred + (size_t)b * CH * img,
        pred + (size_t)b * CH * img + img,
        pred + (size_t)b * CH * img + 2 * img,
        gt   + (size_t)b * CH * img,
        gt   + (size_t)b * CH * img + img,
        gt   + (size_t)b * CH * img + 2 * img };

    // shared 32-bit voffsets (one per input row, reused across all 6 planes)
    unsigned off[4];
#pragma unroll
    for (int i = 0; i < 4; ++i) off[i] = (unsigned)rws[i] * IMG_W + (unsigned)c0;

    // ---- halo loads first (R11 lesson: last-issued halo forces full drain) ----
    float hx[4][CH], hy[4][CH];
    if (is_edge) {
        const unsigned hbase = (unsigned)hcol - (unsigned)c0;  // constant delta
#pragma unroll
        for (int i = 0; i < 4; ++i) {
            const unsigned ho = off[i] + hbase;
#pragma unroll
            for (int c = 0; c < CH; ++c) {
                hx[i][c] = pb[c][ho];
                hy[i][c] = pb[CH + c][ho];
            }
        }
    }

    // ---- main 24 packed-pair loads ----
    f32x2 qx[4][CH], qy[4][CH];
#pragma unroll
    for (int i = 0; i < 4; ++i) {
#pragma unroll
        for (int c = 0; c < CH; ++c) {
            qx[i][c] = *reinterpret_cast<const f32x2*>(pb[c]      + off[i]);
            qy[i][c] = *reinterpret_cast<const f32x2*>(pb[CH + c] + off[i]);
        }
    }

    // window accumulators, packed over the 2 output columns
    f32x2 Ax[CH], Ay[CH], Aw[CH], Ap[CH];   // rows -1,0,1 -> out r0
    f32x2 Bx[CH], By[CH], Bw[CH], Bp[CH];   // rows 0,1,2  -> out r0+1

#define CONSUME(I, DOA, FIRSTA, DOB, FIRSTB)                                \
    _Pragma("unroll")                                                       \
    for (int c = 0; c < CH; ++c) {                                          \
        const f32x2 qxv = qx[I][c], qyv = qy[I][c];                         \
        float xm = __shfl_up(qxv.y, 1),  ym = __shfl_up(qyv.y, 1);          \
        float xp = __shfl_down(qxv.x, 1), yp = __shfl_down(qyv.x, 1);       \
        if (l0)   { xm = hx[I][c]; ym = hy[I][c]; }                         \
        if (l63)  { xp = hx[I][c]; yp = hy[I][c]; }                         \
        if (limg) { xm = qxv.y; ym = qyv.y; }      /* reflect(-1)=1 */      \
        if (rimg) { xp = qxv.x; yp = qyv.x; }      /* reflect(1920)=1918 */ \
        const f32x2 X0 = { xm, qxv.x }, X2 = { qxv.y, xp };                 \
        const f32x2 Y0 = { ym, qyv.x }, Y2 = { qyv.y, yp };                 \
        const f32x2 WX = X0 + qxv + X2;                                     \
        const f32x2 WY = Y0 + qyv + Y2;                                     \
        const f32x2 WP = FMA2(X2, Y2, FMA2(qxv, qyv, X0 * Y0));             \
        const f32x2 WW = FMA2(X2, X2, FMA2(Y2, Y2, FMA2(qxv, qxv,           \
                         FMA2(qyv, qyv, FMA2(X0, X0, Y0 * Y0)))));          \
        if (DOA) {                                                          \
            if (FIRSTA) { Ax[c] = WX; Ay[c] = WY; Aw[c] = WW; Ap[c] = WP; } \
            else        { Ax[c] += WX; Ay[c] += WY;                         \
                          Aw[c] += WW; Ap[c] += WP; }                       \
        }                                                                   \
        if (DOB) {                                                          \
            if (FIRSTB) { Bx[c] = WX; By[c] = WY; Bw[c] = WW; Bp[c] = WP; } \
            else        { Bx[c] += WX; By[c] += WY;                         \
                          Bw[c] += WW; Bp[c] += WP; }                       \
        }                                                                   \
    }

    CONSUME(0, true, true,  false, false)   // row r0-1 -> A
    CONSUME(1, true, false, true,  true)    // row r0   -> A, B
    CONSUME(2, true, false, true,  false)   // row r0+1 -> A, B
    CONSUME(3, false, false, true, false)   // row r0+2 -> B
#undef CONSUME

    // L1 terms from raw center rows (row idx 1 -> out r0, idx 2 -> out r0+1)
    f32x2 l1r0 = zero_, l1r1 = zero_;
#pragma unroll
    for (int c = 0; c < CH; ++c) {
#if __has_builtin(__builtin_elementwise_abs)
        l1r0 += __builtin_elementwise_abs(qx[1][c] - qy[1][c]);
        l1r1 += __builtin_elementwise_abs(qx[2][c] - qy[2][c]);
#else
        f32x2 d0 = qx[1][c] - qy[1][c], d1 = qx[2][c] - qy[2][c];
        d0.x = fabsf(d0.x); d0.y = fabsf(d0.y);
        d1.x = fabsf(d1.x); d1.y = fabsf(d1.y);
        l1r0 += d0; l1r1 += d1;
#endif
    }

    // ---- packed SSIM epilogue (moments scaled by 81; cancels in n/d) ----
#define SSIM2(AX, AY, AW, AP, ACC)                                          \
    {                                                                       \
        const f32x2 u  = (AX) * (AY);                                       \
        const f32x2 v  = FMA2((AY), (AY), (AX) * (AX));                     \
        const f32x2 n1 = FMA2(two_, u, k1_);                                \
        const f32x2 n2 = FMA2(e18_, (AP), FMA2(m2_, u, k2_));               \
        const f32x2 d1 = v + k1_;                                           \
        const f32x2 d2 = FMA2(n9_, (AW), k2_) - v;                          \
        const f32x2 nd = n1 * n2, dd = d1 * d2;                             \
        f32x2 rc;                                                           \
        rc.x = __builtin_amdgcn_rcpf(dd.x);                                 \
        rc.y = __builtin_amdgcn_rcpf(dd.y);                                 \
        f32x2 s = FMA2(mh_, nd * rc, h_);                                   \
        s = __builtin_elementwise_min(                                      \
                __builtin_elementwise_max(s, zero_), one_);                 \
        ACC = FMA2(a3_, s, ACC);                                            \
    }

    f32x2 o0 = b3_ * l1r0;
    f32x2 o1 = b3_ * l1r1;
#pragma unroll
    for (int c = 0; c < CH; ++c) {
        SSIM2(Ax[c], Ay[c], Aw[c], Ap[c], o0)
        SSIM2(Bx[c], By[c], Bw[c], Bp[c], o1)
    }
#undef SSIM2

    float* op = out + ((size_t)b * IMG_H + r0) * IMG_W + c0;
    *reinterpret_cast<f32x2*>(op) = o0;
    *reinterpret_cast<f32x2*>(op + IMG_W) = o1;
}

extern "C" void kernel_launch(void* const* d_in, const int* in_sizes, int n_in,
                              void* d_out, int out_size, void* d_ws, size_t ws_size,
                              hipStream_t stream) {
    const float* pred = (const float*)d_in[0];
    const float* gt   = (const float*)d_in[1];
    float* out = (float*)d_out;

    dim3 block(64, 4, 1);
    dim3 grid(IMG_W / 128, IMG_H / 8, 4);   // 15 x 135 x 4
    dssim_l1_kernel<<<grid, block, 0, stream>>>(pred, gt, out);
}